// Round 15
// baseline (266.089 us; speedup 1.0000x reference)
//
#include <hip/hip_runtime.h>

#define D 128
#define RS 16       // readout sub-blocks per graph
#define NBMAX 1024  // max dst-buckets (64 nodes each)
#define CSH 13      // src-chunk shift: 8192 rows/chunk = 2.1 MB bf16 (fits XCD L2)
#define NCH 8       // chunk slots (src < 65536)
constexpr float EPS = 1e-5f;

typedef short bf16x8 __attribute__((ext_vector_type(8)));
typedef float f32x4 __attribute__((ext_vector_type(4)));
typedef uint u32x4 __attribute__((ext_vector_type(4)));
typedef unsigned long long u64;

__device__ __forceinline__ uint f2bf(float f) {  // RNE f32->bf16 (finite inputs)
  union { float f; uint u; } v; v.f = f;
  return (v.u + 0x7fffu + ((v.u >> 16) & 1u)) >> 16;
}
__device__ __forceinline__ float bflo(uint u) {
  union { uint u; float f; } v; v.u = u << 16; return v.f;
}
__device__ __forceinline__ float bfhi(uint u) {
  union { uint u; float f; } v; v.u = u & 0xffff0000u; return v.f;
}

__device__ __forceinline__ int lower_bound(const int* __restrict__ a, int n, int key) {
  int lo = 0, hi = n;
  while (lo < hi) { int m = (lo + hi) >> 1; if (a[m] < key) lo = m + 1; else hi = m; }
  return lo;
}

// ---------- A: fused preprocessing ----------
__global__ __launch_bounds__(256) void k_pre(
    const int* __restrict__ src, const int* __restrict__ dst,
    int* __restrict__ ocnt, int* __restrict__ btot, int E, int nb, int ebA,
    const float4* __restrict__ x, uint4* __restrict__ xb, int n8, int cb,
    const float* __restrict__ W1, const float* __restrict__ W2,
    const float* __restrict__ W3, ushort* __restrict__ Wf) {
  __shared__ int hloc[NBMAX];
  int bid = blockIdx.x;
  int tid = threadIdx.x;
  if (bid < ebA) {
    for (int j = tid; j < nb; j += 256) hloc[j] = 0;
    __syncthreads();
    int e0 = bid * 4096;
#pragma unroll 4
    for (int it = 0; it < 16; ++it) {
      int e = e0 + it * 256 + tid;
      if (e < E) {
        atomicAdd(&ocnt[src[e]], 1);
        atomicAdd(&hloc[dst[e] >> 6], 1);
      }
    }
    __syncthreads();
    for (int j = tid; j < nb; j += 256) {
      int c = hloc[j];
      if (c) atomicAdd(&btot[j], c);
    }
  } else if (bid < ebA + cb) {
    int i = (bid - ebA) * 256 + tid;
    if (i < n8) {
      float4 p = x[i * 2], q = x[i * 2 + 1];
      uint4 o;
      o.x = f2bf(p.x) | (f2bf(p.y) << 16);
      o.y = f2bf(p.z) | (f2bf(p.w) << 16);
      o.z = f2bf(q.x) | (f2bf(q.y) << 16);
      o.w = f2bf(q.z) | (f2bf(q.w) << 16);
      xb[i] = o;
    }
  } else {
    // W frag layout: frag (ks,ct), lane l holds B[k][col]: k=ks*32+(l>>4)*8+j, col=ct*16+(l&15)
    int t4 = (bid - ebA - cb) * 256 + tid;
    if (t4 < 3 * 2048) {
      const float* Wsrc = (t4 < 2048) ? W1 : (t4 < 4096) ? W2 : W3;
      int t = t4 & 2047;
      int lane = t & 63;
      int frag = t >> 6;
      int ks = frag >> 3, ct = frag & 7;
      int col = ct * 16 + (lane & 15);
      int kb = ks * 32 + (lane >> 4) * 8;
      uint p[8];
#pragma unroll
      for (int j = 0; j < 8; ++j) p[j] = f2bf(Wsrc[(kb + j) * D + col]);
      uint4 o;
      o.x = p[0] | (p[1] << 16);
      o.y = p[2] | (p[3] << 16);
      o.z = p[4] | (p[5] << 16);
      o.w = p[6] | (p[7] << 16);
      *(uint4*)(Wf + (size_t)t4 * 8) = o;
    }
  }
}

// ---------- out-norm from ocnt ----------
__global__ void k_onorm(const int* __restrict__ ocnt, float* __restrict__ outn, int N) {
  int n = blockIdx.x * 256 + threadIdx.x;
  if (n < N) outn[n] = rsqrtf(fmaxf((float)ocnt[n], 1.0f));
}

// ---------- B: exclusive scan of bucket totals (nb <= 1024) ----------
__global__ __launch_bounds__(1024) void k_bbase(const int* __restrict__ btot,
                                                int* __restrict__ bb,
                                                int* __restrict__ rowptr,
                                                int nb, int E, int N) {
  __shared__ int part[1024];
  int t = threadIdx.x;
  int v = (t < nb) ? btot[t] : 0;
  part[t] = v;
  __syncthreads();
  for (int off = 1; off < 1024; off <<= 1) {
    int u = (t >= off) ? part[t - off] : 0;
    __syncthreads();
    part[t] += u;
    __syncthreads();
  }
  if (t < nb) bb[t] = part[t] - v;  // exclusive
  if (t == 0) { bb[nb] = E; rowptr[N] = E; }
}

// ---------- C: scatter edges into bucket regions via atomic range reservation ----------
// pack: [63:32] coef bits (mean(w)*0.25*outn[src]), [21:16] dst&63, [15:0] src
__global__ __launch_bounds__(256) void k_bscatter(
    const int* __restrict__ src, const int* __restrict__ dst,
    const float4* __restrict__ w, const float* __restrict__ outn,
    const int* __restrict__ bb, int* __restrict__ bcur,
    u64* __restrict__ ebuf, int E, int nb) {
  __shared__ int hloc[NBMAX];
  __shared__ int hcur[NBMAX];
  int bid = blockIdx.x, tid = threadIdx.x;
  for (int j = tid; j < nb; j += 256) hloc[j] = 0;
  __syncthreads();
  int e0 = bid * 4096;
#pragma unroll 4
  for (int it = 0; it < 16; ++it) {
    int e = e0 + it * 256 + tid;
    if (e < E) atomicAdd(&hloc[dst[e] >> 6], 1);
  }
  __syncthreads();
  for (int j = tid; j < nb; j += 256) {
    int c = hloc[j];
    hcur[j] = c ? (bb[j] + atomicAdd(&bcur[j], c)) : 0;  // reserve [base, base+c)
  }
  __syncthreads();
#pragma unroll 4
  for (int it = 0; it < 16; ++it) {
    int e = e0 + it * 256 + tid;
    if (e < E) {
      int d = dst[e], s = src[e];
      int pos = atomicAdd(&hcur[d >> 6], 1);
      float4 wv = w[e];
      float coef = (wv.x + wv.y + wv.z + wv.w) * 0.25f * outn[s];
      u64 pk = ((u64)__float_as_uint(coef) << 32) |
               ((u64)(d & 63) << 16) | (uint)s;
      ebuf[pos] = pk;
    }
  }
}

// ---------- D: per-bucket (node,src-chunk) counting sort -> rowptr/innm + final CSR ----------
// Within each node's segment, edges are ordered by src-chunk (src>>CSH) so the
// gather's working set at any instant is one ~2 MB h-slice (L2-resident).
// ecsr[pos] = coef_bits<<32 | src
__global__ __launch_bounds__(256) void k_bplace(
    const u64* __restrict__ ebuf, const int* __restrict__ bb,
    int* __restrict__ rowptr, float* __restrict__ innm,
    u64* __restrict__ ecsr, int N) {
  __shared__ int cnt[64 * NCH], ex[64 * NCH], cur[64 * NCH], psum[256];
  int b = blockIdx.x, tid = threadIdx.x;
  int base = bb[b];
  int tote = bb[b + 1] - base;
  cnt[2 * tid] = 0; cnt[2 * tid + 1] = 0;
  __syncthreads();
  for (int i = tid; i < tote; i += 256) {
    u64 v = ebuf[base + i];
    int dl = (int)((v >> 16) & 63);
    int c = (int)((v & 0xFFFFu) >> CSH);
    atomicAdd(&cnt[dl * NCH + c], 1);
  }
  __syncthreads();
  // exclusive scan of 512 via 256 pair-sums
  int p = cnt[2 * tid] + cnt[2 * tid + 1];
  psum[tid] = p;
  __syncthreads();
  for (int off = 1; off < 256; off <<= 1) {
    int u = (tid >= off) ? psum[tid - off] : 0;
    __syncthreads();
    psum[tid] += u;
    __syncthreads();
  }
  int excl = psum[tid] - p;
  ex[2 * tid] = excl;
  ex[2 * tid + 1] = excl + cnt[2 * tid];
  cur[2 * tid] = 0; cur[2 * tid + 1] = 0;
  __syncthreads();
  int total = psum[255];
  if (tid < 64) {
    int node = b * 64 + tid;
    if (node < N) {
      int st = ex[tid * NCH];
      int en = (tid < 63) ? ex[(tid + 1) * NCH] : total;
      rowptr[node] = base + st;
      innm[node] = rsqrtf(fmaxf((float)(en - st), 1.0f));
    }
  }
  __syncthreads();
  for (int i = tid; i < tote; i += 256) {
    u64 v = ebuf[base + i];
    int dl = (int)((v >> 16) & 63);
    int c = (int)((v & 0xFFFFu) >> CSH);
    int slot = dl * NCH + c;
    int pos = base + ex[slot] + atomicAdd(&cur[slot], 1);
    ecsr[pos] = (v & 0xFFFFFFFF00000000ull) | (v & 0xFFFFull);
  }
}

// ---------- FUSED layer: 2-wave edge-split gather -> combine -> MFMA -> epilogue ----------
// Block = 2 waves, 16 rows. Wave w takes edges of parity w. Edge lists are
// src-chunk-sorted (k_bplace) so active gather reads stay in one L2-resident
// h-slice. NT loads for ecsr, NT epilogue stores keep L2 clean for h.
__global__ __launch_bounds__(128) void k_fused(
    const ushort* __restrict__ h, const int* __restrict__ rowptr,
    const u64* __restrict__ ecsr,
    const float* __restrict__ innm, const ushort* __restrict__ Wf,
    const float* __restrict__ g, const float* __restrict__ bta,
    void* __restrict__ out, int N, int do_ln) {
  __shared__ float lds[16 * D];  // 8 KiB: combine buffer, then epilogue
  const int lane = threadIdx.x & 63;
  const int wid = threadIdx.x >> 6;
  const int lr = lane & 15, lg = lane >> 4;
  const int row0 = blockIdx.x * 16;
  const int row = row0 + lr;
  const bool valid = row < N;

  int beg = 0, end = 0;
  float sc = 0.f;
  if (valid) { beg = rowptr[row]; end = rowptr[row + 1]; sc = innm[row]; }

  float a0[8], a1[8], a2[8], a3[8];
#pragma unroll
  for (int i = 0; i < 8; ++i) { a0[i] = 0; a1[i] = 0; a2[i] = 0; a3[i] = 0; }

#define EDGE(J)                                                  \
  {                                                              \
    u64 v = __builtin_nontemporal_load(&ecsr[J]);                \
    float cf = __uint_as_float((uint)(v >> 32));                 \
    int s = (int)(v & 0xFFFFFFFFu);                              \
    const ushort* hp = h + (size_t)s * D + lg * 8;               \
    uint4 q0 = *(const uint4*)(hp);                              \
    uint4 q1 = *(const uint4*)(hp + 32);                         \
    uint4 q2 = *(const uint4*)(hp + 64);                         \
    uint4 q3 = *(const uint4*)(hp + 96);                         \
    a0[0] = fmaf(bflo(q0.x), cf, a0[0]); a0[1] = fmaf(bfhi(q0.x), cf, a0[1]); \
    a0[2] = fmaf(bflo(q0.y), cf, a0[2]); a0[3] = fmaf(bfhi(q0.y), cf, a0[3]); \
    a0[4] = fmaf(bflo(q0.z), cf, a0[4]); a0[5] = fmaf(bfhi(q0.z), cf, a0[5]); \
    a0[6] = fmaf(bflo(q0.w), cf, a0[6]); a0[7] = fmaf(bfhi(q0.w), cf, a0[7]); \
    a1[0] = fmaf(bflo(q1.x), cf, a1[0]); a1[1] = fmaf(bfhi(q1.x), cf, a1[1]); \
    a1[2] = fmaf(bflo(q1.y), cf, a1[2]); a1[3] = fmaf(bfhi(q1.y), cf, a1[3]); \
    a1[4] = fmaf(bflo(q1.z), cf, a1[4]); a1[5] = fmaf(bfhi(q1.z), cf, a1[5]); \
    a1[6] = fmaf(bflo(q1.w), cf, a1[6]); a1[7] = fmaf(bfhi(q1.w), cf, a1[7]); \
    a2[0] = fmaf(bflo(q2.x), cf, a2[0]); a2[1] = fmaf(bfhi(q2.x), cf, a2[1]); \
    a2[2] = fmaf(bflo(q2.y), cf, a2[2]); a2[3] = fmaf(bfhi(q2.y), cf, a2[3]); \
    a2[4] = fmaf(bflo(q2.z), cf, a2[4]); a2[5] = fmaf(bfhi(q2.z), cf, a2[5]); \
    a2[6] = fmaf(bflo(q2.w), cf, a2[6]); a2[7] = fmaf(bfhi(q2.w), cf, a2[7]); \
    a3[0] = fmaf(bflo(q3.x), cf, a3[0]); a3[1] = fmaf(bfhi(q3.x), cf, a3[1]); \
    a3[2] = fmaf(bflo(q3.y), cf, a3[2]); a3[3] = fmaf(bfhi(q3.y), cf, a3[3]); \
    a3[4] = fmaf(bflo(q3.z), cf, a3[4]); a3[5] = fmaf(bfhi(q3.z), cf, a3[5]); \
    a3[6] = fmaf(bflo(q3.w), cf, a3[6]); a3[7] = fmaf(bfhi(q3.w), cf, a3[7]); \
  }

  // edges of parity `wid`, 2x unrolled for memory-level parallelism
  int j = beg + wid;
  for (; j + 2 < end; j += 4) { EDGE(j) EDGE(j + 2) }
  if (j < end) EDGE(j)
#undef EDGE

  // wave 1 -> LDS partials (lane-major: 2 lanes/bank = conflict-free), then exit
  if (wid == 1) {
#pragma unroll
    for (int i = 0; i < 8; ++i) {
      lds[i * 64 + lane]        = a0[i];
      lds[(i + 8) * 64 + lane]  = a1[i];
      lds[(i + 16) * 64 + lane] = a2[i];
      lds[(i + 24) * 64 + lane] = a3[i];
    }
  }
  __syncthreads();
  if (wid == 1) return;
#pragma unroll
  for (int i = 0; i < 8; ++i) {
    a0[i] += lds[i * 64 + lane];
    a1[i] += lds[(i + 8) * 64 + lane];
    a2[i] += lds[(i + 16) * 64 + lane];
    a3[i] += lds[(i + 24) * 64 + lane];
  }
  asm volatile("s_waitcnt lgkmcnt(0)" ::: "memory");  // combine reads done before LDS reuse
  __builtin_amdgcn_sched_barrier(0);

  // pack A fragments (scale by in_norm), bf16
  uint4 fa[4];
#define PACK(dst, A)                                             \
  dst.x = f2bf(A[0] * sc) | (f2bf(A[1] * sc) << 16);             \
  dst.y = f2bf(A[2] * sc) | (f2bf(A[3] * sc) << 16);             \
  dst.z = f2bf(A[4] * sc) | (f2bf(A[5] * sc) << 16);             \
  dst.w = f2bf(A[6] * sc) | (f2bf(A[7] * sc) << 16);
  PACK(fa[0], a0) PACK(fa[1], a1) PACK(fa[2], a2) PACK(fa[3], a3)
#undef PACK

  // MFMA: 4 ksteps x 8 coltiles
  f32x4 acc[8];
#pragma unroll
  for (int ct = 0; ct < 8; ++ct) acc[ct] = (f32x4){0.f, 0.f, 0.f, 0.f};
#pragma unroll
  for (int ks = 0; ks < 4; ++ks) {
    bf16x8 av;
    __builtin_memcpy(&av, &fa[ks], 16);
    const ushort* wp = Wf + ((size_t)(ks * 8) * 64 + lane) * 8;
#pragma unroll
    for (int ct = 0; ct < 8; ++ct) {
      bf16x8 b = *(const bf16x8*)(wp + ct * 512);
      acc[ct] = __builtin_amdgcn_mfma_f32_16x16x32_bf16(av, b, acc[ct], 0, 0, 0);
    }
  }

  // epilogue: C/D frag row=(lg*4+j), col=ct*16+lr  (wave 0 only; LDS reused)
  if (do_ln) {
    float v[8][4];
#pragma unroll
    for (int ct = 0; ct < 8; ++ct)
#pragma unroll
      for (int j2 = 0; j2 < 4; ++j2) v[ct][j2] = fmaxf(acc[ct][j2], 0.f);
    float mu[4], rs[4];
#pragma unroll
    for (int j2 = 0; j2 < 4; ++j2) {
      float s = 0.f;
#pragma unroll
      for (int ct = 0; ct < 8; ++ct) s += v[ct][j2];
#pragma unroll
      for (int off = 1; off < 16; off <<= 1) s += __shfl_xor(s, off);
      mu[j2] = s * (1.0f / D);
    }
#pragma unroll
    for (int j2 = 0; j2 < 4; ++j2) {
      float q = 0.f;
#pragma unroll
      for (int ct = 0; ct < 8; ++ct) {
        v[ct][j2] -= mu[j2];
        q = fmaf(v[ct][j2], v[ct][j2], q);
      }
#pragma unroll
      for (int off = 1; off < 16; off <<= 1) q += __shfl_xor(q, off);
      rs[j2] = rsqrtf(q * (1.0f / D) + EPS);
    }
    ushort* lp = (ushort*)&lds[0];
#pragma unroll
    for (int ct = 0; ct < 8; ++ct) {
      float gc = g[ct * 16 + lr], bc = bta[ct * 16 + lr];
#pragma unroll
      for (int j2 = 0; j2 < 4; ++j2)
        lp[(lg * 4 + j2) * D + ct * 16 + lr] = (ushort)f2bf(fmaf(v[ct][j2] * rs[j2], gc, bc));
    }
    __builtin_amdgcn_wave_barrier();
    int r = row0 + (lane >> 2);
    if (r < N) {
      ushort* ob = (ushort*)out + (size_t)row0 * D + lane * 32;
#pragma unroll
      for (int i = 0; i < 4; ++i)
        __builtin_nontemporal_store(((const u32x4*)(lp + lane * 32))[i], (u32x4*)ob + i);
    }
  } else {
    float* lp = &lds[0];
#pragma unroll
    for (int ct = 0; ct < 8; ++ct)
#pragma unroll
      for (int j2 = 0; j2 < 4; ++j2)
        lp[(lg * 4 + j2) * D + ct * 16 + lr] = acc[ct][j2];
    __builtin_amdgcn_wave_barrier();
    int r = row0 + (lane >> 2);
    if (r < N) {
      float* ob = (float*)out + (size_t)row0 * D + lane * 32;
#pragma unroll
      for (int i = 0; i < 8; ++i)
        __builtin_nontemporal_store(((const f32x4*)(lp + lane * 32))[i], (f32x4*)ob + i);
    }
  }
}

// ---------- readout stage 1: partial sums, RS blocks per graph ----------
__global__ __launch_bounds__(128) void k_rpart(
    const float* __restrict__ h, const int* __restrict__ gid,
    float* __restrict__ part, int N) {
  int b = blockIdx.x / RS, s = blockIdx.x % RS;
  int t = threadIdx.x;
  int start = lower_bound(gid, N, b);
  int end = lower_bound(gid, N, b + 1);
  int len = end - start;
  int chunk = (len + RS - 1) / RS;
  int rb = start + s * chunk;
  int re = min(rb + chunk, end);
  float acc = 0.f;
  for (int n = rb; n < re; ++n) acc += h[(size_t)n * D + t];
  part[((size_t)b * RS + s) * D + t] = acc;
}

// ---------- readout stage 2 ----------
__global__ __launch_bounds__(128) void k_rsum(
    const float* __restrict__ part, float* __restrict__ out) {
  int b = blockIdx.x;
  int t = threadIdx.x;
  float acc = 0.f;
#pragma unroll
  for (int s = 0; s < RS; ++s) acc += part[((size_t)b * RS + s) * D + t];
  out[(size_t)b * D + t] = acc;
}

extern "C" void kernel_launch(void* const* d_in, const int* in_sizes, int n_in,
                              void* d_out, int out_size, void* d_ws, size_t ws_size,
                              hipStream_t stream) {
  const float* x    = (const float*)d_in[0];
  const float* w    = (const float*)d_in[1];
  const float* W1   = (const float*)d_in[2];
  const float* W2   = (const float*)d_in[3];
  const float* W3   = (const float*)d_in[4];
  const float* ln1g = (const float*)d_in[5];
  const float* ln1b = (const float*)d_in[6];
  const float* ln2g = (const float*)d_in[7];
  const float* ln2b = (const float*)d_in[8];
  const int* src = (const int*)d_in[9];
  const int* dst = (const int*)d_in[10];
  const int* gid = (const int*)d_in[11];
  const int N = in_sizes[0] / D;
  const int E = in_sizes[9];
  const int B = out_size / D;
  float* outp = (float*)d_out;

  // workspace layout (8B alignment kept for ecsr)
  float*  h3f  = (float*)d_ws;                   // [N*D] f32 layer-3 out; ebuf aliases it
  ushort* xb   = (ushort*)(h3f + (size_t)N * D); // [N*D] bf16 (x, then h2)
  ushort* hb1  = xb + (size_t)N * D;             // [N*D] bf16 (h1)
  ushort* Wf   = hb1 + (size_t)N * D;            // [3*2048*8]
  float*  outn = (float*)(Wf + 3 * 2048 * 8);    // [N]
  float*  innm = outn + N;                       // [N]
  const int nb  = (N + 63) >> 6;                 // dst buckets
  const int ebA = (E + 4095) / 4096;             // edge blocks (4096 edges each)
  int*    ocnt = (int*)(innm + N);               // [N]    -- memset region start
  int*    btot = ocnt + N;                       // [nb]
  int*    bcur = btot + nb;                      // [nb]   -- memset region end
  int*    rowptr = bcur + nb;                    // [N+2] (padded even)
  int*    bb   = rowptr + N + 2;                 // [nb+2] (padded even)
  u64*    ecsr = (u64*)(bb + nb + 2);            // [E]
  float*  part = (float*)(ecsr + E);             // [B*RS*D]
  u64*    ebuf = (u64*)h3f;                      // [E] aliases h3f

  const int mb  = (N + 15) / 16;   // 16 rows per block (2 waves)
  const int n8  = N * D / 8;
  const int cb  = (n8 + 255) / 256;

  // ---- CSR build (bucketed, reservation-based; chunk-sorted rows) ----
  hipMemsetAsync(ocnt, 0, sizeof(int) * ((size_t)N + 2 * nb), stream);
  k_pre<<<ebA + cb + 24, 256, 0, stream>>>(src, dst, ocnt, btot, E, nb, ebA,
                                           (const float4*)x, (uint4*)xb, n8, cb,
                                           W1, W2, W3, Wf);
  k_onorm<<<(N + 255) / 256, 256, 0, stream>>>(ocnt, outn, N);
  k_bbase<<<1, 1024, 0, stream>>>(btot, bb, rowptr, nb, E, N);
  k_bscatter<<<ebA, 256, 0, stream>>>(src, dst, (const float4*)w, outn, bb, bcur,
                                      ebuf, E, nb);
  k_bplace<<<nb, 256, 0, stream>>>(ebuf, bb, rowptr, innm, ecsr, N);

  // ---- 3 fused layers (2 waves / 16 rows) ----
  k_fused<<<mb, 128, 0, stream>>>(xb, rowptr, ecsr, innm, Wf,
                                  ln1g, ln1b, hb1, N, 1);
  k_fused<<<mb, 128, 0, stream>>>(hb1, rowptr, ecsr, innm, Wf + 16384,
                                  ln2g, ln2b, xb, N, 1);
  k_fused<<<mb, 128, 0, stream>>>(xb, rowptr, ecsr, innm, Wf + 32768,
                                  nullptr, nullptr, h3f, N, 0);

  // ---- readout ----
  k_rpart<<<B * RS, 128, 0, stream>>>(h3f, gid, part, N);
  k_rsum<<<B, 128, 0, stream>>>(part, outp);
}

// Round 16
// 221.408 us; speedup vs baseline: 1.2018x; 1.2018x over previous
//
#include <hip/hip_runtime.h>

#define D 128
#define RS 16       // readout sub-blocks per graph
#define NBMAX 1024  // max dst-buckets (64 nodes each); N<=65536 (src packs in 16 bits)
constexpr float EPS = 1e-5f;

typedef short bf16x8 __attribute__((ext_vector_type(8)));
typedef float f32x4 __attribute__((ext_vector_type(4)));
typedef unsigned long long u64;

__device__ __forceinline__ uint f2bf(float f) {  // RNE f32->bf16 (finite inputs)
  union { float f; uint u; } v; v.f = f;
  return (v.u + 0x7fffu + ((v.u >> 16) & 1u)) >> 16;
}
__device__ __forceinline__ float bflo(uint u) {
  union { uint u; float f; } v; v.u = u << 16; return v.f;
}
__device__ __forceinline__ float bfhi(uint u) {
  union { uint u; float f; } v; v.u = u & 0xffff0000u; return v.f;
}

__device__ __forceinline__ int lower_bound(const int* __restrict__ a, int n, int key) {
  int lo = 0, hi = n;
  while (lo < hi) { int m = (lo + hi) >> 1; if (a[m] < key) lo = m + 1; else hi = m; }
  return lo;
}

// ---------- A: fused preprocessing ----------
// blocks [0,ebA): ocnt global atomics (0.8M, the floor) + LDS dst-bucket hist ->
//                 one atomicAdd per (block,bucket) into btot
// blocks [ebA,ebA+cb): x -> bf16   |   blocks [ebA+cb, +24): W -> frag layout
__global__ __launch_bounds__(256) void k_pre(
    const int* __restrict__ src, const int* __restrict__ dst,
    int* __restrict__ ocnt, int* __restrict__ btot, int E, int nb, int ebA,
    const float4* __restrict__ x, uint4* __restrict__ xb, int n8, int cb,
    const float* __restrict__ W1, const float* __restrict__ W2,
    const float* __restrict__ W3, ushort* __restrict__ Wf) {
  __shared__ int hloc[NBMAX];
  int bid = blockIdx.x;
  int tid = threadIdx.x;
  if (bid < ebA) {
    for (int j = tid; j < nb; j += 256) hloc[j] = 0;
    __syncthreads();
    int e0 = bid * 4096;
#pragma unroll 4
    for (int it = 0; it < 16; ++it) {
      int e = e0 + it * 256 + tid;
      if (e < E) {
        atomicAdd(&ocnt[src[e]], 1);
        atomicAdd(&hloc[dst[e] >> 6], 1);
      }
    }
    __syncthreads();
    for (int j = tid; j < nb; j += 256) {
      int c = hloc[j];
      if (c) atomicAdd(&btot[j], c);
    }
  } else if (bid < ebA + cb) {
    int i = (bid - ebA) * 256 + tid;
    if (i < n8) {
      float4 p = x[i * 2], q = x[i * 2 + 1];
      uint4 o;
      o.x = f2bf(p.x) | (f2bf(p.y) << 16);
      o.y = f2bf(p.z) | (f2bf(p.w) << 16);
      o.z = f2bf(q.x) | (f2bf(q.y) << 16);
      o.w = f2bf(q.z) | (f2bf(q.w) << 16);
      xb[i] = o;
    }
  } else {
    // W frag layout: frag (ks,ct), lane l holds B[k][col]: k=ks*32+(l>>4)*8+j, col=ct*16+(l&15)
    int t4 = (bid - ebA - cb) * 256 + tid;
    if (t4 < 3 * 2048) {
      const float* Wsrc = (t4 < 2048) ? W1 : (t4 < 4096) ? W2 : W3;
      int t = t4 & 2047;
      int lane = t & 63;
      int frag = t >> 6;
      int ks = frag >> 3, ct = frag & 7;
      int col = ct * 16 + (lane & 15);
      int kb = ks * 32 + (lane >> 4) * 8;
      uint p[8];
#pragma unroll
      for (int j = 0; j < 8; ++j) p[j] = f2bf(Wsrc[(kb + j) * D + col]);
      uint4 o;
      o.x = p[0] | (p[1] << 16);
      o.y = p[2] | (p[3] << 16);
      o.z = p[4] | (p[5] << 16);
      o.w = p[6] | (p[7] << 16);
      *(uint4*)(Wf + (size_t)t4 * 8) = o;
    }
  }
}

// ---------- out-norm from ocnt ----------
__global__ void k_onorm(const int* __restrict__ ocnt, float* __restrict__ outn, int N) {
  int n = blockIdx.x * 256 + threadIdx.x;
  if (n < N) outn[n] = rsqrtf(fmaxf((float)ocnt[n], 1.0f));
}

// ---------- B: exclusive scan of bucket totals (nb <= 1024) ----------
__global__ __launch_bounds__(1024) void k_bbase(const int* __restrict__ btot,
                                                int* __restrict__ bb,
                                                int* __restrict__ rowptr,
                                                int nb, int E, int N) {
  __shared__ int part[1024];
  int t = threadIdx.x;
  int v = (t < nb) ? btot[t] : 0;
  part[t] = v;
  __syncthreads();
  for (int off = 1; off < 1024; off <<= 1) {
    int u = (t >= off) ? part[t - off] : 0;
    __syncthreads();
    part[t] += u;
    __syncthreads();
  }
  if (t < nb) bb[t] = part[t] - v;  // exclusive
  if (t == 0) { bb[nb] = E; rowptr[N] = E; }
}

// ---------- C: scatter edges into bucket regions via atomic range reservation ----------
// pack: [63:32] coef bits (mean(w)*0.25*outn[src]), [21:16] dst&63, [15:0] src
__global__ __launch_bounds__(256) void k_bscatter(
    const int* __restrict__ src, const int* __restrict__ dst,
    const float4* __restrict__ w, const float* __restrict__ outn,
    const int* __restrict__ bb, int* __restrict__ bcur,
    u64* __restrict__ ebuf, int E, int nb) {
  __shared__ int hloc[NBMAX];
  __shared__ int hcur[NBMAX];
  int bid = blockIdx.x, tid = threadIdx.x;
  for (int j = tid; j < nb; j += 256) hloc[j] = 0;
  __syncthreads();
  int e0 = bid * 4096;
#pragma unroll 4
  for (int it = 0; it < 16; ++it) {
    int e = e0 + it * 256 + tid;
    if (e < E) atomicAdd(&hloc[dst[e] >> 6], 1);
  }
  __syncthreads();
  for (int j = tid; j < nb; j += 256) {
    int c = hloc[j];
    hcur[j] = c ? (bb[j] + atomicAdd(&bcur[j], c)) : 0;  // reserve [base, base+c)
  }
  __syncthreads();
#pragma unroll 4
  for (int it = 0; it < 16; ++it) {
    int e = e0 + it * 256 + tid;
    if (e < E) {
      int d = dst[e], s = src[e];
      int pos = atomicAdd(&hcur[d >> 6], 1);
      float4 wv = w[e];
      float coef = (wv.x + wv.y + wv.z + wv.w) * 0.25f * outn[s];
      u64 pk = ((u64)__float_as_uint(coef) << 32) |
               ((u64)(d & 63) << 16) | (uint)s;
      ebuf[pos] = pk;
    }
  }
}

// ---------- D: per-bucket count -> innm+rowptr (non-atomic) + final CSR (packed u64) ----------
// ecsr[pos] = coef_bits<<32 | src
__global__ __launch_bounds__(256) void k_bplace(
    const u64* __restrict__ ebuf, const int* __restrict__ bb,
    int* __restrict__ rowptr, float* __restrict__ innm,
    u64* __restrict__ ecsr, int N) {
  __shared__ int c64[64], ex[64], cur[64];
  int b = blockIdx.x, tid = threadIdx.x;
  int base = bb[b];
  int cnt = bb[b + 1] - base;
  if (tid < 64) c64[tid] = 0;
  __syncthreads();
  for (int i = tid; i < cnt; i += 256) {
    u64 v = ebuf[base + i];
    atomicAdd(&c64[(int)((v >> 16) & 63)], 1);
  }
  __syncthreads();
  if (tid < 64) {  // wave 0: scan 64 counts
    int cv = c64[tid];
    int inc = cv;
#pragma unroll
    for (int off = 1; off < 64; off <<= 1) {
      int u = __shfl_up(inc, off);
      if (tid >= off) inc += u;
    }
    int excl = inc - cv;
    ex[tid] = excl;
    cur[tid] = 0;
    int node = b * 64 + tid;
    if (node < N) {
      rowptr[node] = base + excl;
      innm[node] = rsqrtf(fmaxf((float)cv, 1.0f));
    }
  }
  __syncthreads();
  for (int i = tid; i < cnt; i += 256) {
    u64 v = ebuf[base + i];
    int dl = (int)((v >> 16) & 63);
    int pos = base + ex[dl] + atomicAdd(&cur[dl], 1);
    ecsr[pos] = (v & 0xFFFFFFFF00000000ull) | (v & 0xFFFFull);
  }
}

// ---------- FUSED layer (round-11 best): gather->LDS A-tile -> MFMA -> epilogue ----------
// 4 waves/block, wave owns 16 rows. Phase A: 16-lane groups gather 4 rows each
// (4x unrolled, 256B/edge contiguous) into wave-private [16][136] LDS tile.
// Phase B: A-fragments from LDS, 4 ksteps x 8 coltiles MFMA, fused LN / f32 out.
// LDS strictly wave-private -> no block barriers; tail waves may return early.
__global__ __launch_bounds__(256) void k_fused(
    const ushort* __restrict__ h, const int* __restrict__ rowptr,
    const u64* __restrict__ ecsr,
    const float* __restrict__ innm, const ushort* __restrict__ Wf,
    const float* __restrict__ g, const float* __restrict__ bta,
    void* __restrict__ out, int N, int do_ln) {
  __shared__ float lds[4][16 * D];  // 8 KiB per wave (A-tile, then epilogue)
  const int lane = threadIdx.x & 63;
  const int wv = threadIdx.x >> 6;
  const int row0 = blockIdx.x * 64 + wv * 16;
  if (row0 >= N) return;

  // ---- phase A: gather 16 rows into LDS tile [16][136]
  ushort* at = (ushort*)&lds[wv][0];
  {
    const int grp = lane >> 4;  // 4 groups of 16 lanes
    const int c = lane & 15;    // lane's col-octet (8 bf16 = 16 B)
    for (int rr = 0; rr < 4; ++rr) {
      int n = row0 + grp * 4 + rr;  // uniform within group
      if (n >= N) break;
      int beg = rowptr[n], end = rowptr[n + 1];
      float a0 = 0, a1 = 0, a2 = 0, a3 = 0, a4 = 0, a5 = 0, a6 = 0, a7 = 0;
#define ACC8(q, f)                                          \
  a0 = fmaf(bflo(q.x), f, a0); a1 = fmaf(bfhi(q.x), f, a1); \
  a2 = fmaf(bflo(q.y), f, a2); a3 = fmaf(bfhi(q.y), f, a3); \
  a4 = fmaf(bflo(q.z), f, a4); a5 = fmaf(bfhi(q.z), f, a5); \
  a6 = fmaf(bflo(q.w), f, a6); a7 = fmaf(bfhi(q.w), f, a7);
      int j = beg;
      for (; j + 4 <= end; j += 4) {
        u64 v0 = ecsr[j], v1 = ecsr[j + 1], v2 = ecsr[j + 2], v3 = ecsr[j + 3];
        const ushort* p0 = h + (size_t)(v0 & 0xFFFFu) * D + c * 8;
        const ushort* p1 = h + (size_t)(v1 & 0xFFFFu) * D + c * 8;
        const ushort* p2 = h + (size_t)(v2 & 0xFFFFu) * D + c * 8;
        const ushort* p3 = h + (size_t)(v3 & 0xFFFFu) * D + c * 8;
        float f0 = __uint_as_float((uint)(v0 >> 32));
        float f1 = __uint_as_float((uint)(v1 >> 32));
        float f2 = __uint_as_float((uint)(v2 >> 32));
        float f3 = __uint_as_float((uint)(v3 >> 32));
        uint4 q0 = *(const uint4*)p0;
        uint4 q1 = *(const uint4*)p1;
        uint4 q2 = *(const uint4*)p2;
        uint4 q3 = *(const uint4*)p3;
        ACC8(q0, f0) ACC8(q1, f1) ACC8(q2, f2) ACC8(q3, f3)
      }
      for (; j < end; ++j) {
        u64 v = ecsr[j];
        float f = __uint_as_float((uint)(v >> 32));
        uint4 q = *(const uint4*)(h + (size_t)(v & 0xFFFFu) * D + c * 8);
        ACC8(q, f)
      }
#undef ACC8
      float sc = innm[n];
      uint4 o;
      o.x = f2bf(a0 * sc) | (f2bf(a1 * sc) << 16);
      o.y = f2bf(a2 * sc) | (f2bf(a3 * sc) << 16);
      o.z = f2bf(a4 * sc) | (f2bf(a5 * sc) << 16);
      o.w = f2bf(a6 * sc) | (f2bf(a7 * sc) << 16);
      *(uint4*)(at + (grp * 4 + rr) * 136 + c * 8) = o;
    }
  }
  asm volatile("s_waitcnt lgkmcnt(0)" ::: "memory");
  __builtin_amdgcn_sched_barrier(0);

  // ---- phase B: MFMA from LDS A-tile
  const int lc = lane & 15, lg = lane >> 4;
  f32x4 acc[8];
#pragma unroll
  for (int ct = 0; ct < 8; ++ct) acc[ct] = (f32x4){0.f, 0.f, 0.f, 0.f};
#pragma unroll
  for (int ks = 0; ks < 4; ++ks) {
    bf16x8 a = *(const bf16x8*)(at + lc * 136 + ks * 32 + lg * 8);
    const ushort* wp = Wf + ((size_t)(ks * 8) * 64 + lane) * 8;
#pragma unroll
    for (int ct = 0; ct < 8; ++ct) {
      bf16x8 b = *(const bf16x8*)(wp + ct * 512);
      acc[ct] = __builtin_amdgcn_mfma_f32_16x16x32_bf16(a, b, acc[ct], 0, 0, 0);
    }
  }
  asm volatile("s_waitcnt lgkmcnt(0)" ::: "memory");  // A-tile dead; slot reused below
  __builtin_amdgcn_sched_barrier(0);

  if (do_ln) {
    float v[8][4];
#pragma unroll
    for (int ct = 0; ct < 8; ++ct)
#pragma unroll
      for (int j = 0; j < 4; ++j) v[ct][j] = fmaxf(acc[ct][j], 0.f);
    float mu[4], rs[4];
#pragma unroll
    for (int j = 0; j < 4; ++j) {
      float s = 0.f;
#pragma unroll
      for (int ct = 0; ct < 8; ++ct) s += v[ct][j];
#pragma unroll
      for (int off = 1; off < 16; off <<= 1) s += __shfl_xor(s, off);
      mu[j] = s * (1.0f / D);
    }
#pragma unroll
    for (int j = 0; j < 4; ++j) {
      float q = 0.f;
#pragma unroll
      for (int ct = 0; ct < 8; ++ct) {
        v[ct][j] -= mu[j];
        q = fmaf(v[ct][j], v[ct][j], q);
      }
#pragma unroll
      for (int off = 1; off < 16; off <<= 1) q += __shfl_xor(q, off);
      rs[j] = rsqrtf(q * (1.0f / D) + EPS);
    }
    ushort* lp = (ushort*)&lds[wv][0];
#pragma unroll
    for (int ct = 0; ct < 8; ++ct) {
      float gc = g[ct * 16 + lc], bc = bta[ct * 16 + lc];
#pragma unroll
      for (int j = 0; j < 4; ++j)
        lp[(lg * 4 + j) * D + ct * 16 + lc] = (ushort)f2bf(fmaf(v[ct][j] * rs[j], gc, bc));
    }
    __builtin_amdgcn_wave_barrier();
    int r = row0 + (lane >> 2);  // lane copies 32 ushorts = quarter row
    if (r < N) {
      ushort* ob = (ushort*)out + (size_t)row0 * D + lane * 32;
#pragma unroll
      for (int i = 0; i < 4; ++i)
        ((uint4*)ob)[i] = ((const uint4*)(lp + lane * 32))[i];
    }
  } else {
    float* lp = &lds[wv][0];
#pragma unroll
    for (int ct = 0; ct < 8; ++ct)
#pragma unroll
      for (int j = 0; j < 4; ++j)
        lp[(lg * 4 + j) * D + ct * 16 + lc] = acc[ct][j];
    __builtin_amdgcn_wave_barrier();
    int r = row0 + (lane >> 2);  // lane copies 32 floats = quarter row
    if (r < N) {
      float* ob = (float*)out + (size_t)row0 * D + lane * 32;
#pragma unroll
      for (int i = 0; i < 8; ++i)
        ((float4*)ob)[i] = ((const float4*)(lp + lane * 32))[i];
    }
  }
}

// ---------- readout stage 1: partial sums, RS blocks per graph ----------
__global__ __launch_bounds__(128) void k_rpart(
    const float* __restrict__ h, const int* __restrict__ gid,
    float* __restrict__ part, int N) {
  int b = blockIdx.x / RS, s = blockIdx.x % RS;
  int t = threadIdx.x;
  int start = lower_bound(gid, N, b);
  int end = lower_bound(gid, N, b + 1);
  int len = end - start;
  int chunk = (len + RS - 1) / RS;
  int rb = start + s * chunk;
  int re = min(rb + chunk, end);
  float acc = 0.f;
  for (int n = rb; n < re; ++n) acc += h[(size_t)n * D + t];
  part[((size_t)b * RS + s) * D + t] = acc;
}

// ---------- readout stage 2 ----------
__global__ __launch_bounds__(128) void k_rsum(
    const float* __restrict__ part, float* __restrict__ out) {
  int b = blockIdx.x;
  int t = threadIdx.x;
  float acc = 0.f;
#pragma unroll
  for (int s = 0; s < RS; ++s) acc += part[((size_t)b * RS + s) * D + t];
  out[(size_t)b * D + t] = acc;
}

extern "C" void kernel_launch(void* const* d_in, const int* in_sizes, int n_in,
                              void* d_out, int out_size, void* d_ws, size_t ws_size,
                              hipStream_t stream) {
  const float* x    = (const float*)d_in[0];
  const float* w    = (const float*)d_in[1];
  const float* W1   = (const float*)d_in[2];
  const float* W2   = (const float*)d_in[3];
  const float* W3   = (const float*)d_in[4];
  const float* ln1g = (const float*)d_in[5];
  const float* ln1b = (const float*)d_in[6];
  const float* ln2g = (const float*)d_in[7];
  const float* ln2b = (const float*)d_in[8];
  const int* src = (const int*)d_in[9];
  const int* dst = (const int*)d_in[10];
  const int* gid = (const int*)d_in[11];
  const int N = in_sizes[0] / D;
  const int E = in_sizes[9];
  const int B = out_size / D;
  float* outp = (float*)d_out;

  // workspace layout (8B alignment kept for ecsr)
  float*  h3f  = (float*)d_ws;                   // [N*D] f32 layer-3 out; ebuf aliases it
  ushort* xb   = (ushort*)(h3f + (size_t)N * D); // [N*D] bf16 (x, then h2)
  ushort* hb1  = xb + (size_t)N * D;             // [N*D] bf16 (h1)
  ushort* Wf   = hb1 + (size_t)N * D;            // [3*2048*8]
  float*  outn = (float*)(Wf + 3 * 2048 * 8);    // [N]
  float*  innm = outn + N;                       // [N]
  const int nb  = (N + 63) >> 6;                 // dst buckets
  const int ebA = (E + 4095) / 4096;             // edge blocks (4096 edges each)
  int*    ocnt = (int*)(innm + N);               // [N]    -- memset region start
  int*    btot = ocnt + N;                       // [nb]
  int*    bcur = btot + nb;                      // [nb]   -- memset region end
  int*    rowptr = bcur + nb;                    // [N+2] (padded even)
  int*    bb   = rowptr + N + 2;                 // [nb+2] (padded even)
  u64*    ecsr = (u64*)(bb + nb + 2);            // [E]
  float*  part = (float*)(ecsr + E);             // [B*RS*D]
  u64*    ebuf = (u64*)h3f;                      // [E] aliases h3f

  const int mb  = (N + 63) / 64;   // 64 rows per block (4 waves x 16 rows)
  const int n8  = N * D / 8;
  const int cb  = (n8 + 255) / 256;

  // ---- CSR build (bucketed, reservation-based) ----
  hipMemsetAsync(ocnt, 0, sizeof(int) * ((size_t)N + 2 * nb), stream);
  k_pre<<<ebA + cb + 24, 256, 0, stream>>>(src, dst, ocnt, btot, E, nb, ebA,
                                           (const float4*)x, (uint4*)xb, n8, cb,
                                           W1, W2, W3, Wf);
  k_onorm<<<(N + 255) / 256, 256, 0, stream>>>(ocnt, outn, N);
  k_bbase<<<1, 1024, 0, stream>>>(btot, bb, rowptr, nb, E, N);
  k_bscatter<<<ebA, 256, 0, stream>>>(src, dst, (const float4*)w, outn, bb, bcur,
                                      ebuf, E, nb);
  k_bplace<<<nb, 256, 0, stream>>>(ebuf, bb, rowptr, innm, ecsr, N);

  // ---- 3 fused layers (4 waves x 16 rows per block) ----
  k_fused<<<mb, 256, 0, stream>>>(xb, rowptr, ecsr, innm, Wf,
                                  ln1g, ln1b, hb1, N, 1);
  k_fused<<<mb, 256, 0, stream>>>(hb1, rowptr, ecsr, innm, Wf + 16384,
                                  ln2g, ln2b, xb, N, 1);
  k_fused<<<mb, 256, 0, stream>>>(xb, rowptr, ecsr, innm, Wf + 32768,
                                  nullptr, nullptr, h3f, N, 0);

  // ---- readout ----
  k_rpart<<<B * RS, 128, 0, stream>>>(h3f, gid, part, N);
  k_rsum<<<B, 128, 0, stream>>>(part, outp);
}

// Round 17
// 212.438 us; speedup vs baseline: 1.2525x; 1.0422x over previous
//
#include <hip/hip_runtime.h>

#define D 128
#define RS 16       // readout sub-blocks per graph
#define NBMAX 1024  // max buckets (64 nodes each); N<=65536 (src packs in 16 bits)
constexpr float EPS = 1e-5f;

typedef short bf16x8 __attribute__((ext_vector_type(8)));
typedef float f32x4 __attribute__((ext_vector_type(4)));
typedef unsigned long long u64;

__device__ __forceinline__ uint f2bf(float f) {  // RNE f32->bf16 (finite inputs)
  union { float f; uint u; } v; v.f = f;
  return (v.u + 0x7fffu + ((v.u >> 16) & 1u)) >> 16;
}
__device__ __forceinline__ float bflo(uint u) {
  union { uint u; float f; } v; v.u = u << 16; return v.f;
}
__device__ __forceinline__ float bfhi(uint u) {
  union { uint u; float f; } v; v.u = u & 0xffff0000u; return v.f;
}

__device__ __forceinline__ int lower_bound(const int* __restrict__ a, int n, int key) {
  int lo = 0, hi = n;
  while (lo < hi) { int m = (lo + hi) >> 1; if (a[m] < key) lo = m + 1; else hi = m; }
  return lo;
}

// ---------- A: fused preprocessing (NO per-node global atomics) ----------
// blocks [0,ebA): LDS hists of dst>>6 AND src>>6; one atomicAdd/(block,bucket)
// blocks [ebA,ebA+cb): x -> bf16   |   blocks [ebA+cb, +24): W -> frag layout
__global__ __launch_bounds__(256) void k_pre(
    const int* __restrict__ src, const int* __restrict__ dst,
    int* __restrict__ btot, int* __restrict__ btot2, int E, int nb, int ebA,
    const float4* __restrict__ x, uint4* __restrict__ xb, int n8, int cb,
    const float* __restrict__ W1, const float* __restrict__ W2,
    const float* __restrict__ W3, ushort* __restrict__ Wf) {
  __shared__ int hd[NBMAX];
  __shared__ int hs[NBMAX];
  int bid = blockIdx.x;
  int tid = threadIdx.x;
  if (bid < ebA) {
    for (int j = tid; j < nb; j += 256) { hd[j] = 0; hs[j] = 0; }
    __syncthreads();
    int e0 = bid * 4096;
#pragma unroll 4
    for (int it = 0; it < 16; ++it) {
      int e = e0 + it * 256 + tid;
      if (e < E) {
        atomicAdd(&hd[dst[e] >> 6], 1);
        atomicAdd(&hs[src[e] >> 6], 1);
      }
    }
    __syncthreads();
    for (int j = tid; j < nb; j += 256) {
      int cd = hd[j];
      if (cd) atomicAdd(&btot[j], cd);
      int cs = hs[j];
      if (cs) atomicAdd(&btot2[j], cs);
    }
  } else if (bid < ebA + cb) {
    int i = (bid - ebA) * 256 + tid;
    if (i < n8) {
      float4 p = x[i * 2], q = x[i * 2 + 1];
      uint4 o;
      o.x = f2bf(p.x) | (f2bf(p.y) << 16);
      o.y = f2bf(p.z) | (f2bf(p.w) << 16);
      o.z = f2bf(q.x) | (f2bf(q.y) << 16);
      o.w = f2bf(q.z) | (f2bf(q.w) << 16);
      xb[i] = o;
    }
  } else {
    // W frag layout: frag (ks,ct), lane l holds B[k][col]: k=ks*32+(l>>4)*8+j, col=ct*16+(l&15)
    int t4 = (bid - ebA - cb) * 256 + tid;
    if (t4 < 3 * 2048) {
      const float* Wsrc = (t4 < 2048) ? W1 : (t4 < 4096) ? W2 : W3;
      int t = t4 & 2047;
      int lane = t & 63;
      int frag = t >> 6;
      int ks = frag >> 3, ct = frag & 7;
      int col = ct * 16 + (lane & 15);
      int kb = ks * 32 + (lane >> 4) * 8;
      uint p[8];
#pragma unroll
      for (int j = 0; j < 8; ++j) p[j] = f2bf(Wsrc[(kb + j) * D + col]);
      uint4 o;
      o.x = p[0] | (p[1] << 16);
      o.y = p[2] | (p[3] << 16);
      o.z = p[4] | (p[5] << 16);
      o.w = p[6] | (p[7] << 16);
      *(uint4*)(Wf + (size_t)t4 * 8) = o;
    }
  }
}

// ---------- B: exclusive scans of both bucket-total arrays ----------
__global__ __launch_bounds__(1024) void k_bbase(
    const int* __restrict__ btot, const int* __restrict__ btot2,
    int* __restrict__ bb, int* __restrict__ bb2,
    int* __restrict__ rowptr, int nb, int E, int N) {
  __shared__ int part[1024];
  int t = threadIdx.x;
  // scan 1: dst buckets
  int v = (t < nb) ? btot[t] : 0;
  part[t] = v;
  __syncthreads();
  for (int off = 1; off < 1024; off <<= 1) {
    int u = (t >= off) ? part[t - off] : 0;
    __syncthreads();
    part[t] += u;
    __syncthreads();
  }
  if (t < nb) bb[t] = part[t] - v;
  if (t == 0) { bb[nb] = E; rowptr[N] = E; }
  __syncthreads();
  // scan 2: src buckets
  int v2 = (t < nb) ? btot2[t] : 0;
  part[t] = v2;
  __syncthreads();
  for (int off = 1; off < 1024; off <<= 1) {
    int u = (t >= off) ? part[t - off] : 0;
    __syncthreads();
    part[t] += u;
    __syncthreads();
  }
  if (t < nb) bb2[t] = part[t] - v2;
  if (t == 0) bb2[nb] = E;
}

// ---------- C: scatter edges into dst-bucket regions (u64) AND src-bucket regions (u32) ----------
// dst pack: [63:32] meanw bits (mean(w)*0.25 -- outn applied later), [21:16] dst&63, [15:0] src
__global__ __launch_bounds__(256) void k_bscatter(
    const int* __restrict__ src, const int* __restrict__ dst,
    const float4* __restrict__ w,
    const int* __restrict__ bb, int* __restrict__ bcur,
    const int* __restrict__ bb2, int* __restrict__ bcur2,
    u64* __restrict__ ebuf, uint* __restrict__ ebuf2, int E, int nb) {
  __shared__ int hd[NBMAX], hdc[NBMAX];
  __shared__ int hsv[NBMAX], hsc[NBMAX];
  int bid = blockIdx.x, tid = threadIdx.x;
  for (int j = tid; j < nb; j += 256) { hd[j] = 0; hsv[j] = 0; }
  __syncthreads();
  int e0 = bid * 4096;
#pragma unroll 4
  for (int it = 0; it < 16; ++it) {
    int e = e0 + it * 256 + tid;
    if (e < E) {
      atomicAdd(&hd[dst[e] >> 6], 1);
      atomicAdd(&hsv[src[e] >> 6], 1);
    }
  }
  __syncthreads();
  for (int j = tid; j < nb; j += 256) {
    int cd = hd[j];
    hdc[j] = cd ? (bb[j] + atomicAdd(&bcur[j], cd)) : 0;   // reserve dst range
    int cs = hsv[j];
    hsc[j] = cs ? (bb2[j] + atomicAdd(&bcur2[j], cs)) : 0;  // reserve src range
  }
  __syncthreads();
#pragma unroll 4
  for (int it = 0; it < 16; ++it) {
    int e = e0 + it * 256 + tid;
    if (e < E) {
      int d = dst[e], s = src[e];
      int pos = atomicAdd(&hdc[d >> 6], 1);
      float4 wv = w[e];
      float meanw = (wv.x + wv.y + wv.z + wv.w) * 0.25f;
      u64 pk = ((u64)__float_as_uint(meanw) << 32) |
               ((u64)(d & 63) << 16) | (uint)s;
      ebuf[pos] = pk;
      int pos2 = atomicAdd(&hsc[s >> 6], 1);
      ebuf2[pos2] = (uint)s;
    }
  }
}

// ---------- C2: per-src-bucket count -> outn (non-atomic global write) ----------
__global__ __launch_bounds__(256) void k_scount(
    const uint* __restrict__ ebuf2, const int* __restrict__ bb2,
    float* __restrict__ outn, int N) {
  __shared__ int c64[64];
  int b = blockIdx.x, tid = threadIdx.x;
  int base = bb2[b];
  int cnt = bb2[b + 1] - base;
  if (tid < 64) c64[tid] = 0;
  __syncthreads();
  for (int i = tid; i < cnt; i += 256)
    atomicAdd(&c64[ebuf2[base + i] & 63], 1);
  __syncthreads();
  if (tid < 64) {
    int node = b * 64 + tid;
    if (node < N) outn[node] = rsqrtf(fmaxf((float)c64[tid], 1.0f));
  }
}

// ---------- D: per-dst-bucket count -> innm+rowptr + final CSR (coef = meanw*outn[src]) ----------
// ecsr[pos] = coef_bits<<32 | src
__global__ __launch_bounds__(256) void k_bplace(
    const u64* __restrict__ ebuf, const int* __restrict__ bb,
    const float* __restrict__ outn,
    int* __restrict__ rowptr, float* __restrict__ innm,
    u64* __restrict__ ecsr, int N) {
  __shared__ int c64[64], ex[64], cur[64];
  int b = blockIdx.x, tid = threadIdx.x;
  int base = bb[b];
  int cnt = bb[b + 1] - base;
  if (tid < 64) c64[tid] = 0;
  __syncthreads();
  for (int i = tid; i < cnt; i += 256) {
    u64 v = ebuf[base + i];
    atomicAdd(&c64[(int)((v >> 16) & 63)], 1);
  }
  __syncthreads();
  if (tid < 64) {  // wave 0: scan 64 counts
    int cv = c64[tid];
    int inc = cv;
#pragma unroll
    for (int off = 1; off < 64; off <<= 1) {
      int u = __shfl_up(inc, off);
      if (tid >= off) inc += u;
    }
    int excl = inc - cv;
    ex[tid] = excl;
    cur[tid] = 0;
    int node = b * 64 + tid;
    if (node < N) {
      rowptr[node] = base + excl;
      innm[node] = rsqrtf(fmaxf((float)cv, 1.0f));
    }
  }
  __syncthreads();
  for (int i = tid; i < cnt; i += 256) {
    u64 v = ebuf[base + i];
    int dl = (int)((v >> 16) & 63);
    int s = (int)(v & 0xFFFFu);
    float coef = __uint_as_float((uint)(v >> 32)) * outn[s];
    int pos = base + ex[dl] + atomicAdd(&cur[dl], 1);
    ecsr[pos] = ((u64)__float_as_uint(coef) << 32) | (uint)s;
  }
}

// ---------- FUSED layer (round-11 best): gather->LDS A-tile -> MFMA -> epilogue ----------
// 4 waves/block, wave owns 16 rows. Phase A: 16-lane groups gather 4 rows each
// (4x unrolled, 256B/edge contiguous) into wave-private [16][136] LDS tile.
// Phase B: A-fragments from LDS, 4 ksteps x 8 coltiles MFMA, fused LN / f32 out.
// LDS strictly wave-private -> no block barriers; tail waves may return early.
__global__ __launch_bounds__(256) void k_fused(
    const ushort* __restrict__ h, const int* __restrict__ rowptr,
    const u64* __restrict__ ecsr,
    const float* __restrict__ innm, const ushort* __restrict__ Wf,
    const float* __restrict__ g, const float* __restrict__ bta,
    void* __restrict__ out, int N, int do_ln) {
  __shared__ float lds[4][16 * D];  // 8 KiB per wave (A-tile, then epilogue)
  const int lane = threadIdx.x & 63;
  const int wv = threadIdx.x >> 6;
  const int row0 = blockIdx.x * 64 + wv * 16;
  if (row0 >= N) return;

  // ---- phase A: gather 16 rows into LDS tile [16][136]
  ushort* at = (ushort*)&lds[wv][0];
  {
    const int grp = lane >> 4;  // 4 groups of 16 lanes
    const int c = lane & 15;    // lane's col-octet (8 bf16 = 16 B)
    for (int rr = 0; rr < 4; ++rr) {
      int n = row0 + grp * 4 + rr;  // uniform within group
      if (n >= N) break;
      int beg = rowptr[n], end = rowptr[n + 1];
      float a0 = 0, a1 = 0, a2 = 0, a3 = 0, a4 = 0, a5 = 0, a6 = 0, a7 = 0;
#define ACC8(q, f)                                          \
  a0 = fmaf(bflo(q.x), f, a0); a1 = fmaf(bfhi(q.x), f, a1); \
  a2 = fmaf(bflo(q.y), f, a2); a3 = fmaf(bfhi(q.y), f, a3); \
  a4 = fmaf(bflo(q.z), f, a4); a5 = fmaf(bfhi(q.z), f, a5); \
  a6 = fmaf(bflo(q.w), f, a6); a7 = fmaf(bfhi(q.w), f, a7);
      int j = beg;
      for (; j + 4 <= end; j += 4) {
        u64 v0 = ecsr[j], v1 = ecsr[j + 1], v2 = ecsr[j + 2], v3 = ecsr[j + 3];
        const ushort* p0 = h + (size_t)(v0 & 0xFFFFu) * D + c * 8;
        const ushort* p1 = h + (size_t)(v1 & 0xFFFFu) * D + c * 8;
        const ushort* p2 = h + (size_t)(v2 & 0xFFFFu) * D + c * 8;
        const ushort* p3 = h + (size_t)(v3 & 0xFFFFu) * D + c * 8;
        float f0 = __uint_as_float((uint)(v0 >> 32));
        float f1 = __uint_as_float((uint)(v1 >> 32));
        float f2 = __uint_as_float((uint)(v2 >> 32));
        float f3 = __uint_as_float((uint)(v3 >> 32));
        uint4 q0 = *(const uint4*)p0;
        uint4 q1 = *(const uint4*)p1;
        uint4 q2 = *(const uint4*)p2;
        uint4 q3 = *(const uint4*)p3;
        ACC8(q0, f0) ACC8(q1, f1) ACC8(q2, f2) ACC8(q3, f3)
      }
      for (; j < end; ++j) {
        u64 v = ecsr[j];
        float f = __uint_as_float((uint)(v >> 32));
        uint4 q = *(const uint4*)(h + (size_t)(v & 0xFFFFu) * D + c * 8);
        ACC8(q, f)
      }
#undef ACC8
      float sc = innm[n];
      uint4 o;
      o.x = f2bf(a0 * sc) | (f2bf(a1 * sc) << 16);
      o.y = f2bf(a2 * sc) | (f2bf(a3 * sc) << 16);
      o.z = f2bf(a4 * sc) | (f2bf(a5 * sc) << 16);
      o.w = f2bf(a6 * sc) | (f2bf(a7 * sc) << 16);
      *(uint4*)(at + (grp * 4 + rr) * 136 + c * 8) = o;
    }
  }
  asm volatile("s_waitcnt lgkmcnt(0)" ::: "memory");
  __builtin_amdgcn_sched_barrier(0);

  // ---- phase B: MFMA from LDS A-tile
  const int lc = lane & 15, lg = lane >> 4;
  f32x4 acc[8];
#pragma unroll
  for (int ct = 0; ct < 8; ++ct) acc[ct] = (f32x4){0.f, 0.f, 0.f, 0.f};
#pragma unroll
  for (int ks = 0; ks < 4; ++ks) {
    bf16x8 a = *(const bf16x8*)(at + lc * 136 + ks * 32 + lg * 8);
    const ushort* wp = Wf + ((size_t)(ks * 8) * 64 + lane) * 8;
#pragma unroll
    for (int ct = 0; ct < 8; ++ct) {
      bf16x8 b = *(const bf16x8*)(wp + ct * 512);
      acc[ct] = __builtin_amdgcn_mfma_f32_16x16x32_bf16(a, b, acc[ct], 0, 0, 0);
    }
  }
  asm volatile("s_waitcnt lgkmcnt(0)" ::: "memory");  // A-tile dead; slot reused below
  __builtin_amdgcn_sched_barrier(0);

  if (do_ln) {
    float v[8][4];
#pragma unroll
    for (int ct = 0; ct < 8; ++ct)
#pragma unroll
      for (int j = 0; j < 4; ++j) v[ct][j] = fmaxf(acc[ct][j], 0.f);
    float mu[4], rs[4];
#pragma unroll
    for (int j = 0; j < 4; ++j) {
      float s = 0.f;
#pragma unroll
      for (int ct = 0; ct < 8; ++ct) s += v[ct][j];
#pragma unroll
      for (int off = 1; off < 16; off <<= 1) s += __shfl_xor(s, off);
      mu[j] = s * (1.0f / D);
    }
#pragma unroll
    for (int j = 0; j < 4; ++j) {
      float q = 0.f;
#pragma unroll
      for (int ct = 0; ct < 8; ++ct) {
        v[ct][j] -= mu[j];
        q = fmaf(v[ct][j], v[ct][j], q);
      }
#pragma unroll
      for (int off = 1; off < 16; off <<= 1) q += __shfl_xor(q, off);
      rs[j] = rsqrtf(q * (1.0f / D) + EPS);
    }
    ushort* lp = (ushort*)&lds[wv][0];
#pragma unroll
    for (int ct = 0; ct < 8; ++ct) {
      float gc = g[ct * 16 + lc], bc = bta[ct * 16 + lc];
#pragma unroll
      for (int j = 0; j < 4; ++j)
        lp[(lg * 4 + j) * D + ct * 16 + lc] = (ushort)f2bf(fmaf(v[ct][j] * rs[j], gc, bc));
    }
    __builtin_amdgcn_wave_barrier();
    int r = row0 + (lane >> 2);  // lane copies 32 ushorts = quarter row
    if (r < N) {
      ushort* ob = (ushort*)out + (size_t)row0 * D + lane * 32;
#pragma unroll
      for (int i = 0; i < 4; ++i)
        ((uint4*)ob)[i] = ((const uint4*)(lp + lane * 32))[i];
    }
  } else {
    float* lp = &lds[wv][0];
#pragma unroll
    for (int ct = 0; ct < 8; ++ct)
#pragma unroll
      for (int j = 0; j < 4; ++j)
        lp[(lg * 4 + j) * D + ct * 16 + lc] = acc[ct][j];
    __builtin_amdgcn_wave_barrier();
    int r = row0 + (lane >> 2);  // lane copies 32 floats = quarter row
    if (r < N) {
      float* ob = (float*)out + (size_t)row0 * D + lane * 32;
#pragma unroll
      for (int i = 0; i < 8; ++i)
        ((float4*)ob)[i] = ((const float4*)(lp + lane * 32))[i];
    }
  }
}

// ---------- readout stage 1: partial sums, RS blocks per graph ----------
__global__ __launch_bounds__(128) void k_rpart(
    const float* __restrict__ h, const int* __restrict__ gid,
    float* __restrict__ part, int N) {
  int b = blockIdx.x / RS, s = blockIdx.x % RS;
  int t = threadIdx.x;
  int start = lower_bound(gid, N, b);
  int end = lower_bound(gid, N, b + 1);
  int len = end - start;
  int chunk = (len + RS - 1) / RS;
  int rb = start + s * chunk;
  int re = min(rb + chunk, end);
  float acc = 0.f;
  for (int n = rb; n < re; ++n) acc += h[(size_t)n * D + t];
  part[((size_t)b * RS + s) * D + t] = acc;
}

// ---------- readout stage 2 ----------
__global__ __launch_bounds__(128) void k_rsum(
    const float* __restrict__ part, float* __restrict__ out) {
  int b = blockIdx.x;
  int t = threadIdx.x;
  float acc = 0.f;
#pragma unroll
  for (int s = 0; s < RS; ++s) acc += part[((size_t)b * RS + s) * D + t];
  out[(size_t)b * D + t] = acc;
}

extern "C" void kernel_launch(void* const* d_in, const int* in_sizes, int n_in,
                              void* d_out, int out_size, void* d_ws, size_t ws_size,
                              hipStream_t stream) {
  const float* x    = (const float*)d_in[0];
  const float* w    = (const float*)d_in[1];
  const float* W1   = (const float*)d_in[2];
  const float* W2   = (const float*)d_in[3];
  const float* W3   = (const float*)d_in[4];
  const float* ln1g = (const float*)d_in[5];
  const float* ln1b = (const float*)d_in[6];
  const float* ln2g = (const float*)d_in[7];
  const float* ln2b = (const float*)d_in[8];
  const int* src = (const int*)d_in[9];
  const int* dst = (const int*)d_in[10];
  const int* gid = (const int*)d_in[11];
  const int N = in_sizes[0] / D;
  const int E = in_sizes[9];
  const int B = out_size / D;
  float* outp = (float*)d_out;

  // workspace layout (8B alignment kept for ecsr)
  float*  h3f  = (float*)d_ws;                   // [N*D] f32 layer-3 out; ebuf/ebuf2 alias it
  ushort* xb   = (ushort*)(h3f + (size_t)N * D); // [N*D] bf16 (x, then h2)
  ushort* hb1  = xb + (size_t)N * D;             // [N*D] bf16 (h1)
  ushort* Wf   = hb1 + (size_t)N * D;            // [3*2048*8]
  float*  outn = (float*)(Wf + 3 * 2048 * 8);    // [N]
  float*  innm = outn + N;                       // [N]
  const int nb  = (N + 63) >> 6;                 // node buckets (64 nodes)
  const int ebA = (E + 4095) / 4096;             // edge blocks (4096 edges each)
  int*    btot = (int*)(innm + N);               // [nb]  -- memset region start
  int*    bcur = btot + nb;                      // [nb]
  int*    btot2= bcur + nb;                      // [nb]
  int*    bcur2= btot2 + nb;                     // [nb]  -- memset region end
  int*    rowptr = bcur2 + nb;                   // [N+2] (padded even)
  int*    bb   = rowptr + N + 2;                 // [nb+2] (padded even)
  int*    bb2  = bb + nb + 2;                    // [nb+2]
  u64*    ecsr = (u64*)(bb2 + nb + 2);           // [E]
  float*  part = (float*)(ecsr + E);             // [B*RS*D]
  u64*    ebuf = (u64*)h3f;                      // [E] aliases h3f
  uint*   ebuf2= (uint*)(ebuf + E);              // [E] aliases h3f (needs 12E B <= N*D*4)

  const int mb  = (N + 63) / 64;   // 64 rows per block (4 waves x 16 rows)
  const int n8  = N * D / 8;
  const int cb  = (n8 + 255) / 256;

  // ---- CSR build (fully bucketed: no per-node global atomics anywhere) ----
  hipMemsetAsync(btot, 0, sizeof(int) * (size_t)(4 * nb), stream);
  k_pre<<<ebA + cb + 24, 256, 0, stream>>>(src, dst, btot, btot2, E, nb, ebA,
                                           (const float4*)x, (uint4*)xb, n8, cb,
                                           W1, W2, W3, Wf);
  k_bbase<<<1, 1024, 0, stream>>>(btot, btot2, bb, bb2, rowptr, nb, E, N);
  k_bscatter<<<ebA, 256, 0, stream>>>(src, dst, (const float4*)w, bb, bcur,
                                      bb2, bcur2, ebuf, ebuf2, E, nb);
  k_scount<<<nb, 256, 0, stream>>>(ebuf2, bb2, outn, N);
  k_bplace<<<nb, 256, 0, stream>>>(ebuf, bb, outn, rowptr, innm, ecsr, N);

  // ---- 3 fused layers (4 waves x 16 rows per block) ----
  k_fused<<<mb, 256, 0, stream>>>(xb, rowptr, ecsr, innm, Wf,
                                  ln1g, ln1b, hb1, N, 1);
  k_fused<<<mb, 256, 0, stream>>>(hb1, rowptr, ecsr, innm, Wf + 16384,
                                  ln2g, ln2b, xb, N, 1);
  k_fused<<<mb, 256, 0, stream>>>(xb, rowptr, ecsr, innm, Wf + 32768,
                                  nullptr, nullptr, h3f, N, 0);

  // ---- readout ----
  k_rpart<<<B * RS, 128, 0, stream>>>(h3f, gid, part, N);
  k_rsum<<<B, 128, 0, stream>>>(part, outp);
}

// Round 18
// 203.790 us; speedup vs baseline: 1.3057x; 1.0424x over previous
//
#include <hip/hip_runtime.h>

#define D 128
#define RS 16       // readout sub-blocks per graph
#define NBMAX 1024  // max buckets (64 nodes each); N<=65536 (src/dst pack in 16 bits)
constexpr float EPS = 1e-5f;

typedef short bf16x8 __attribute__((ext_vector_type(8)));
typedef float f32x4 __attribute__((ext_vector_type(4)));
typedef unsigned long long u64;

__device__ __forceinline__ uint f2bf(float f) {  // RNE f32->bf16 (finite inputs)
  union { float f; uint u; } v; v.f = f;
  return (v.u + 0x7fffu + ((v.u >> 16) & 1u)) >> 16;
}
__device__ __forceinline__ float bflo(uint u) {
  union { uint u; float f; } v; v.u = u << 16; return v.f;
}
__device__ __forceinline__ float bfhi(uint u) {
  union { uint u; float f; } v; v.u = u & 0xffff0000u; return v.f;
}

__device__ __forceinline__ int lower_bound(const int* __restrict__ a, int n, int key) {
  int lo = 0, hi = n;
  while (lo < hi) { int m = (lo + hi) >> 1; if (a[m] < key) lo = m + 1; else hi = m; }
  return lo;
}

// ---------- A: fused preprocessing (NO per-node global atomics) ----------
// blocks [0,ebA): LDS hists of dst>>6 AND src>>6; one atomicAdd/(block,bucket)
// blocks [ebA,ebA+cb): x -> bf16   |   blocks [ebA+cb, +24): W -> frag layout
__global__ __launch_bounds__(256) void k_pre(
    const int* __restrict__ src, const int* __restrict__ dst,
    int* __restrict__ btot, int* __restrict__ btot2, int E, int nb, int ebA,
    const float4* __restrict__ x, uint4* __restrict__ xb, int n8, int cb,
    const float* __restrict__ W1, const float* __restrict__ W2,
    const float* __restrict__ W3, ushort* __restrict__ Wf) {
  __shared__ int hd[NBMAX];
  __shared__ int hs[NBMAX];
  int bid = blockIdx.x;
  int tid = threadIdx.x;
  if (bid < ebA) {
    for (int j = tid; j < nb; j += 256) { hd[j] = 0; hs[j] = 0; }
    __syncthreads();
    int e0 = bid * 4096;
#pragma unroll 4
    for (int it = 0; it < 16; ++it) {
      int e = e0 + it * 256 + tid;
      if (e < E) {
        atomicAdd(&hd[dst[e] >> 6], 1);
        atomicAdd(&hs[src[e] >> 6], 1);
      }
    }
    __syncthreads();
    for (int j = tid; j < nb; j += 256) {
      int cd = hd[j];
      if (cd) atomicAdd(&btot[j], cd);
      int cs = hs[j];
      if (cs) atomicAdd(&btot2[j], cs);
    }
  } else if (bid < ebA + cb) {
    int i = (bid - ebA) * 256 + tid;
    if (i < n8) {
      float4 p = x[i * 2], q = x[i * 2 + 1];
      uint4 o;
      o.x = f2bf(p.x) | (f2bf(p.y) << 16);
      o.y = f2bf(p.z) | (f2bf(p.w) << 16);
      o.z = f2bf(q.x) | (f2bf(q.y) << 16);
      o.w = f2bf(q.z) | (f2bf(q.w) << 16);
      xb[i] = o;
    }
  } else {
    // W frag layout: frag (ks,ct), lane l holds B[k][col]: k=ks*32+(l>>4)*8+j, col=ct*16+(l&15)
    int t4 = (bid - ebA - cb) * 256 + tid;
    if (t4 < 3 * 2048) {
      const float* Wsrc = (t4 < 2048) ? W1 : (t4 < 4096) ? W2 : W3;
      int t = t4 & 2047;
      int lane = t & 63;
      int frag = t >> 6;
      int ks = frag >> 3, ct = frag & 7;
      int col = ct * 16 + (lane & 15);
      int kb = ks * 32 + (lane >> 4) * 8;
      uint p[8];
#pragma unroll
      for (int j = 0; j < 8; ++j) p[j] = f2bf(Wsrc[(kb + j) * D + col]);
      uint4 o;
      o.x = p[0] | (p[1] << 16);
      o.y = p[2] | (p[3] << 16);
      o.z = p[4] | (p[5] << 16);
      o.w = p[6] | (p[7] << 16);
      *(uint4*)(Wf + (size_t)t4 * 8) = o;
    }
  }
}

// ---------- B: exclusive scans of both bucket-total arrays ----------
__global__ __launch_bounds__(1024) void k_bbase(
    const int* __restrict__ btot, const int* __restrict__ btot2,
    int* __restrict__ bb, int* __restrict__ bb2,
    int* __restrict__ rowptr, int nb, int E, int N) {
  __shared__ int part[1024];
  int t = threadIdx.x;
  // scan 1: dst buckets
  int v = (t < nb) ? btot[t] : 0;
  part[t] = v;
  __syncthreads();
  for (int off = 1; off < 1024; off <<= 1) {
    int u = (t >= off) ? part[t - off] : 0;
    __syncthreads();
    part[t] += u;
    __syncthreads();
  }
  if (t < nb) bb[t] = part[t] - v;
  if (t == 0) { bb[nb] = E; rowptr[N] = E; }
  __syncthreads();
  // scan 2: src buckets
  int v2 = (t < nb) ? btot2[t] : 0;
  part[t] = v2;
  __syncthreads();
  for (int off = 1; off < 1024; off <<= 1) {
    int u = (t >= off) ? part[t - off] : 0;
    __syncthreads();
    part[t] += u;
    __syncthreads();
  }
  if (t < nb) bb2[t] = part[t] - v2;
  if (t == 0) bb2[nb] = E;
}

// ---------- C: block-local LDS counting sort -> coalesced bucket-region writes ----------
// 512 threads, 4096 edges/block. Edges sorted by dst-bucket (u64 pack) and src
// (u32) in LDS, global ranges reserved per bucket, then flushed so consecutive
// LDS slots map to consecutive global addresses (runs coalesce into full lines).
// dst pack: [63:32] meanw bits (mean(w)*0.25), [31:16] dst, [15:0] src
__global__ __launch_bounds__(512) void k_bscatter(
    const int* __restrict__ src, const int* __restrict__ dst,
    const float4* __restrict__ w,
    const int* __restrict__ bb, int* __restrict__ bcur,
    const int* __restrict__ bb2, int* __restrict__ bcur2,
    u64* __restrict__ ebuf, uint* __restrict__ ebuf2, int E, int nb) {
  __shared__ u64 sedge[4096];                  // 32 KB dst-bucket-sorted edges
  __shared__ uint ssrc[4096];                  // 16 KB src-bucket-sorted srcs
  __shared__ int hd[NBMAX], sd[NBMAX], dd[NBMAX];    // hist, scan(->cursor), flush-delta
  __shared__ int hs[NBMAX], s2[NBMAX], d2[NBMAX];
  __shared__ int psum[512];
  int bid = blockIdx.x, tid = threadIdx.x;
  int e0 = bid * 4096;
  int ec = min(4096, E - e0);
  for (int j = tid; j < nb; j += 512) { hd[j] = 0; hs[j] = 0; }
  __syncthreads();
#pragma unroll
  for (int it = 0; it < 8; ++it) {
    int i = it * 512 + tid;
    if (i < ec) {
      atomicAdd(&hd[dst[e0 + i] >> 6], 1);
      atomicAdd(&hs[src[e0 + i] >> 6], 1);
    }
  }
  __syncthreads();
  // exclusive scan hd -> sd (2 elems/thread, nb <= 1024)
  {
    int a0 = (2 * tid < nb) ? hd[2 * tid] : 0;
    int a1 = (2 * tid + 1 < nb) ? hd[2 * tid + 1] : 0;
    int p = a0 + a1;
    psum[tid] = p;
    __syncthreads();
    for (int off = 1; off < 512; off <<= 1) {
      int u = (tid >= off) ? psum[tid - off] : 0;
      __syncthreads();
      psum[tid] += u;
      __syncthreads();
    }
    int ex = psum[tid] - p;
    if (2 * tid < nb) sd[2 * tid] = ex;
    if (2 * tid + 1 < nb) sd[2 * tid + 1] = ex + a0;
  }
  __syncthreads();
  // exclusive scan hs -> s2
  {
    int a0 = (2 * tid < nb) ? hs[2 * tid] : 0;
    int a1 = (2 * tid + 1 < nb) ? hs[2 * tid + 1] : 0;
    int p = a0 + a1;
    psum[tid] = p;
    __syncthreads();
    for (int off = 1; off < 512; off <<= 1) {
      int u = (tid >= off) ? psum[tid - off] : 0;
      __syncthreads();
      psum[tid] += u;
      __syncthreads();
    }
    int ex = psum[tid] - p;
    if (2 * tid < nb) s2[2 * tid] = ex;
    if (2 * tid + 1 < nb) s2[2 * tid + 1] = ex + a0;
  }
  __syncthreads();
  // reserve global ranges; delta = global_start - lds_start (flush: gpos = delta + lds_pos)
  for (int j = tid; j < nb; j += 512) {
    int cd = hd[j];
    dd[j] = cd ? (bb[j] + atomicAdd(&bcur[j], cd) - sd[j]) : 0;
    int cs = hs[j];
    d2[j] = cs ? (bb2[j] + atomicAdd(&bcur2[j], cs) - s2[j]) : 0;
  }
  __syncthreads();
  // place into LDS sorted arrays (sd/s2 now serve as cursors)
#pragma unroll
  for (int it = 0; it < 8; ++it) {
    int i = it * 512 + tid;
    if (i < ec) {
      int d = dst[e0 + i], s = src[e0 + i];
      float4 wv = w[e0 + i];
      float meanw = (wv.x + wv.y + wv.z + wv.w) * 0.25f;
      u64 pk = ((u64)__float_as_uint(meanw) << 32) | ((u64)(uint)d << 16) | (uint)s;
      sedge[atomicAdd(&sd[d >> 6], 1)] = pk;
      ssrc[atomicAdd(&s2[s >> 6], 1)] = (uint)s;
    }
  }
  __syncthreads();
  // flush: within-bucket runs are contiguous in both LDS and global
  for (int i = tid; i < ec; i += 512) {
    u64 v = sedge[i];
    int j = (int)((v >> 16) & 0xFFFFu) >> 6;
    ebuf[dd[j] + i] = v;
    uint s = ssrc[i];
    ebuf2[d2[s >> 6] + i] = s;
  }
}

// ---------- C2: per-src-bucket count -> outn (non-atomic global write) ----------
__global__ __launch_bounds__(256) void k_scount(
    const uint* __restrict__ ebuf2, const int* __restrict__ bb2,
    float* __restrict__ outn, int N) {
  __shared__ int c64[64];
  int b = blockIdx.x, tid = threadIdx.x;
  int base = bb2[b];
  int cnt = bb2[b + 1] - base;
  if (tid < 64) c64[tid] = 0;
  __syncthreads();
  for (int i = tid; i < cnt; i += 256)
    atomicAdd(&c64[ebuf2[base + i] & 63], 1);
  __syncthreads();
  if (tid < 64) {
    int node = b * 64 + tid;
    if (node < N) outn[node] = rsqrtf(fmaxf((float)c64[tid], 1.0f));
  }
}

// ---------- D: per-dst-bucket count -> innm+rowptr + final CSR (coef = meanw*outn[src]) ----------
// ecsr[pos] = coef_bits<<32 | src
__global__ __launch_bounds__(256) void k_bplace(
    const u64* __restrict__ ebuf, const int* __restrict__ bb,
    const float* __restrict__ outn,
    int* __restrict__ rowptr, float* __restrict__ innm,
    u64* __restrict__ ecsr, int N) {
  __shared__ int c64[64], ex[64], cur[64];
  int b = blockIdx.x, tid = threadIdx.x;
  int base = bb[b];
  int cnt = bb[b + 1] - base;
  if (tid < 64) c64[tid] = 0;
  __syncthreads();
  for (int i = tid; i < cnt; i += 256) {
    u64 v = ebuf[base + i];
    atomicAdd(&c64[(int)((v >> 16) & 63)], 1);
  }
  __syncthreads();
  if (tid < 64) {  // wave 0: scan 64 counts
    int cv = c64[tid];
    int inc = cv;
#pragma unroll
    for (int off = 1; off < 64; off <<= 1) {
      int u = __shfl_up(inc, off);
      if (tid >= off) inc += u;
    }
    int excl = inc - cv;
    ex[tid] = excl;
    cur[tid] = 0;
    int node = b * 64 + tid;
    if (node < N) {
      rowptr[node] = base + excl;
      innm[node] = rsqrtf(fmaxf((float)cv, 1.0f));
    }
  }
  __syncthreads();
  for (int i = tid; i < cnt; i += 256) {
    u64 v = ebuf[base + i];
    int dl = (int)((v >> 16) & 63);
    int s = (int)(v & 0xFFFFu);
    float coef = __uint_as_float((uint)(v >> 32)) * outn[s];
    int pos = base + ex[dl] + atomicAdd(&cur[dl], 1);
    ecsr[pos] = ((u64)__float_as_uint(coef) << 32) | (uint)s;
  }
}

// ---------- FUSED layer (round-11 best): gather->LDS A-tile -> MFMA -> epilogue ----------
// 4 waves/block, wave owns 16 rows. Phase A: 16-lane groups gather 4 rows each
// (4x unrolled, 256B/edge contiguous) into wave-private [16][136] LDS tile.
// Phase B: A-fragments from LDS, 4 ksteps x 8 coltiles MFMA, fused LN / f32 out.
// LDS strictly wave-private -> no block barriers; tail waves may return early.
__global__ __launch_bounds__(256) void k_fused(
    const ushort* __restrict__ h, const int* __restrict__ rowptr,
    const u64* __restrict__ ecsr,
    const float* __restrict__ innm, const ushort* __restrict__ Wf,
    const float* __restrict__ g, const float* __restrict__ bta,
    void* __restrict__ out, int N, int do_ln) {
  __shared__ float lds[4][16 * D];  // 8 KiB per wave (A-tile, then epilogue)
  const int lane = threadIdx.x & 63;
  const int wv = threadIdx.x >> 6;
  const int row0 = blockIdx.x * 64 + wv * 16;
  if (row0 >= N) return;

  // ---- phase A: gather 16 rows into LDS tile [16][136]
  ushort* at = (ushort*)&lds[wv][0];
  {
    const int grp = lane >> 4;  // 4 groups of 16 lanes
    const int c = lane & 15;    // lane's col-octet (8 bf16 = 16 B)
    for (int rr = 0; rr < 4; ++rr) {
      int n = row0 + grp * 4 + rr;  // uniform within group
      if (n >= N) break;
      int beg = rowptr[n], end = rowptr[n + 1];
      float a0 = 0, a1 = 0, a2 = 0, a3 = 0, a4 = 0, a5 = 0, a6 = 0, a7 = 0;
#define ACC8(q, f)                                          \
  a0 = fmaf(bflo(q.x), f, a0); a1 = fmaf(bfhi(q.x), f, a1); \
  a2 = fmaf(bflo(q.y), f, a2); a3 = fmaf(bfhi(q.y), f, a3); \
  a4 = fmaf(bflo(q.z), f, a4); a5 = fmaf(bfhi(q.z), f, a5); \
  a6 = fmaf(bflo(q.w), f, a6); a7 = fmaf(bfhi(q.w), f, a7);
      int j = beg;
      for (; j + 4 <= end; j += 4) {
        u64 v0 = ecsr[j], v1 = ecsr[j + 1], v2 = ecsr[j + 2], v3 = ecsr[j + 3];
        const ushort* p0 = h + (size_t)(v0 & 0xFFFFu) * D + c * 8;
        const ushort* p1 = h + (size_t)(v1 & 0xFFFFu) * D + c * 8;
        const ushort* p2 = h + (size_t)(v2 & 0xFFFFu) * D + c * 8;
        const ushort* p3 = h + (size_t)(v3 & 0xFFFFu) * D + c * 8;
        float f0 = __uint_as_float((uint)(v0 >> 32));
        float f1 = __uint_as_float((uint)(v1 >> 32));
        float f2 = __uint_as_float((uint)(v2 >> 32));
        float f3 = __uint_as_float((uint)(v3 >> 32));
        uint4 q0 = *(const uint4*)p0;
        uint4 q1 = *(const uint4*)p1;
        uint4 q2 = *(const uint4*)p2;
        uint4 q3 = *(const uint4*)p3;
        ACC8(q0, f0) ACC8(q1, f1) ACC8(q2, f2) ACC8(q3, f3)
      }
      for (; j < end; ++j) {
        u64 v = ecsr[j];
        float f = __uint_as_float((uint)(v >> 32));
        uint4 q = *(const uint4*)(h + (size_t)(v & 0xFFFFu) * D + c * 8);
        ACC8(q, f)
      }
#undef ACC8
      float sc = innm[n];
      uint4 o;
      o.x = f2bf(a0 * sc) | (f2bf(a1 * sc) << 16);
      o.y = f2bf(a2 * sc) | (f2bf(a3 * sc) << 16);
      o.z = f2bf(a4 * sc) | (f2bf(a5 * sc) << 16);
      o.w = f2bf(a6 * sc) | (f2bf(a7 * sc) << 16);
      *(uint4*)(at + (grp * 4 + rr) * 136 + c * 8) = o;
    }
  }
  asm volatile("s_waitcnt lgkmcnt(0)" ::: "memory");
  __builtin_amdgcn_sched_barrier(0);

  // ---- phase B: MFMA from LDS A-tile
  const int lc = lane & 15, lg = lane >> 4;
  f32x4 acc[8];
#pragma unroll
  for (int ct = 0; ct < 8; ++ct) acc[ct] = (f32x4){0.f, 0.f, 0.f, 0.f};
#pragma unroll
  for (int ks = 0; ks < 4; ++ks) {
    bf16x8 a = *(const bf16x8*)(at + lc * 136 + ks * 32 + lg * 8);
    const ushort* wp = Wf + ((size_t)(ks * 8) * 64 + lane) * 8;
#pragma unroll
    for (int ct = 0; ct < 8; ++ct) {
      bf16x8 b = *(const bf16x8*)(wp + ct * 512);
      acc[ct] = __builtin_amdgcn_mfma_f32_16x16x32_bf16(a, b, acc[ct], 0, 0, 0);
    }
  }
  asm volatile("s_waitcnt lgkmcnt(0)" ::: "memory");  // A-tile dead; slot reused below
  __builtin_amdgcn_sched_barrier(0);

  if (do_ln) {
    float v[8][4];
#pragma unroll
    for (int ct = 0; ct < 8; ++ct)
#pragma unroll
      for (int j = 0; j < 4; ++j) v[ct][j] = fmaxf(acc[ct][j], 0.f);
    float mu[4], rs[4];
#pragma unroll
    for (int j = 0; j < 4; ++j) {
      float s = 0.f;
#pragma unroll
      for (int ct = 0; ct < 8; ++ct) s += v[ct][j];
#pragma unroll
      for (int off = 1; off < 16; off <<= 1) s += __shfl_xor(s, off);
      mu[j] = s * (1.0f / D);
    }
#pragma unroll
    for (int j = 0; j < 4; ++j) {
      float q = 0.f;
#pragma unroll
      for (int ct = 0; ct < 8; ++ct) {
        v[ct][j] -= mu[j];
        q = fmaf(v[ct][j], v[ct][j], q);
      }
#pragma unroll
      for (int off = 1; off < 16; off <<= 1) q += __shfl_xor(q, off);
      rs[j] = rsqrtf(q * (1.0f / D) + EPS);
    }
    ushort* lp = (ushort*)&lds[wv][0];
#pragma unroll
    for (int ct = 0; ct < 8; ++ct) {
      float gc = g[ct * 16 + lc], bc = bta[ct * 16 + lc];
#pragma unroll
      for (int j = 0; j < 4; ++j)
        lp[(lg * 4 + j) * D + ct * 16 + lc] = (ushort)f2bf(fmaf(v[ct][j] * rs[j], gc, bc));
    }
    __builtin_amdgcn_wave_barrier();
    int r = row0 + (lane >> 2);  // lane copies 32 ushorts = quarter row
    if (r < N) {
      ushort* ob = (ushort*)out + (size_t)row0 * D + lane * 32;
#pragma unroll
      for (int i = 0; i < 4; ++i)
        ((uint4*)ob)[i] = ((const uint4*)(lp + lane * 32))[i];
    }
  } else {
    float* lp = &lds[wv][0];
#pragma unroll
    for (int ct = 0; ct < 8; ++ct)
#pragma unroll
      for (int j = 0; j < 4; ++j)
        lp[(lg * 4 + j) * D + ct * 16 + lc] = acc[ct][j];
    __builtin_amdgcn_wave_barrier();
    int r = row0 + (lane >> 2);  // lane copies 32 floats = quarter row
    if (r < N) {
      float* ob = (float*)out + (size_t)row0 * D + lane * 32;
#pragma unroll
      for (int i = 0; i < 8; ++i)
        ((float4*)ob)[i] = ((const float4*)(lp + lane * 32))[i];
    }
  }
}

// ---------- readout stage 1: partial sums, RS blocks per graph ----------
__global__ __launch_bounds__(128) void k_rpart(
    const float* __restrict__ h, const int* __restrict__ gid,
    float* __restrict__ part, int N) {
  int b = blockIdx.x / RS, s = blockIdx.x % RS;
  int t = threadIdx.x;
  int start = lower_bound(gid, N, b);
  int end = lower_bound(gid, N, b + 1);
  int len = end - start;
  int chunk = (len + RS - 1) / RS;
  int rb = start + s * chunk;
  int re = min(rb + chunk, end);
  float acc = 0.f;
  for (int n = rb; n < re; ++n) acc += h[(size_t)n * D + t];
  part[((size_t)b * RS + s) * D + t] = acc;
}

// ---------- readout stage 2 ----------
__global__ __launch_bounds__(128) void k_rsum(
    const float* __restrict__ part, float* __restrict__ out) {
  int b = blockIdx.x;
  int t = threadIdx.x;
  float acc = 0.f;
#pragma unroll
  for (int s = 0; s < RS; ++s) acc += part[((size_t)b * RS + s) * D + t];
  out[(size_t)b * D + t] = acc;
}

extern "C" void kernel_launch(void* const* d_in, const int* in_sizes, int n_in,
                              void* d_out, int out_size, void* d_ws, size_t ws_size,
                              hipStream_t stream) {
  const float* x    = (const float*)d_in[0];
  const float* w    = (const float*)d_in[1];
  const float* W1   = (const float*)d_in[2];
  const float* W2   = (const float*)d_in[3];
  const float* W3   = (const float*)d_in[4];
  const float* ln1g = (const float*)d_in[5];
  const float* ln1b = (const float*)d_in[6];
  const float* ln2g = (const float*)d_in[7];
  const float* ln2b = (const float*)d_in[8];
  const int* src = (const int*)d_in[9];
  const int* dst = (const int*)d_in[10];
  const int* gid = (const int*)d_in[11];
  const int N = in_sizes[0] / D;
  const int E = in_sizes[9];
  const int B = out_size / D;
  float* outp = (float*)d_out;

  // workspace layout (8B alignment kept for ecsr)
  float*  h3f  = (float*)d_ws;                   // [N*D] f32 layer-3 out; ebuf/ebuf2 alias it
  ushort* xb   = (ushort*)(h3f + (size_t)N * D); // [N*D] bf16 (x, then h2)
  ushort* hb1  = xb + (size_t)N * D;             // [N*D] bf16 (h1)
  ushort* Wf   = hb1 + (size_t)N * D;            // [3*2048*8]
  float*  outn = (float*)(Wf + 3 * 2048 * 8);    // [N]
  float*  innm = outn + N;                       // [N]
  const int nb  = (N + 63) >> 6;                 // node buckets (64 nodes)
  const int ebA = (E + 4095) / 4096;             // edge blocks (4096 edges each)
  int*    btot = (int*)(innm + N);               // [nb]  -- memset region start
  int*    bcur = btot + nb;                      // [nb]
  int*    btot2= bcur + nb;                      // [nb]
  int*    bcur2= btot2 + nb;                     // [nb]  -- memset region end
  int*    rowptr = bcur2 + nb;                   // [N+2] (padded even)
  int*    bb   = rowptr + N + 2;                 // [nb+2] (padded even)
  int*    bb2  = bb + nb + 2;                    // [nb+2]
  u64*    ecsr = (u64*)(bb2 + nb + 2);           // [E]
  float*  part = (float*)(ecsr + E);             // [B*RS*D]
  u64*    ebuf = (u64*)h3f;                      // [E] aliases h3f
  uint*   ebuf2= (uint*)(ebuf + E);              // [E] aliases h3f (needs 12E B <= N*D*4)

  const int mb  = (N + 63) / 64;   // 64 rows per block (4 waves x 16 rows)
  const int n8  = N * D / 8;
  const int cb  = (n8 + 255) / 256;

  // ---- CSR build (fully bucketed: no per-node global atomics anywhere) ----
  hipMemsetAsync(btot, 0, sizeof(int) * (size_t)(4 * nb), stream);
  k_pre<<<ebA + cb + 24, 256, 0, stream>>>(src, dst, btot, btot2, E, nb, ebA,
                                           (const float4*)x, (uint4*)xb, n8, cb,
                                           W1, W2, W3, Wf);
  k_bbase<<<1, 1024, 0, stream>>>(btot, btot2, bb, bb2, rowptr, nb, E, N);
  k_bscatter<<<ebA, 512, 0, stream>>>(src, dst, (const float4*)w, bb, bcur,
                                      bb2, bcur2, ebuf, ebuf2, E, nb);
  k_scount<<<nb, 256, 0, stream>>>(ebuf2, bb2, outn, N);
  k_bplace<<<nb, 256, 0, stream>>>(ebuf, bb, outn, rowptr, innm, ecsr, N);

  // ---- 3 fused layers (4 waves x 16 rows per block) ----
  k_fused<<<mb, 256, 0, stream>>>(xb, rowptr, ecsr, innm, Wf,
                                  ln1g, ln1b, hb1, N, 1);
  k_fused<<<mb, 256, 0, stream>>>(hb1, rowptr, ecsr, innm, Wf + 16384,
                                  ln2g, ln2b, xb, N, 1);
  k_fused<<<mb, 256, 0, stream>>>(xb, rowptr, ecsr, innm, Wf + 32768,
                                  nullptr, nullptr, h3f, N, 0);

  // ---- readout ----
  k_rpart<<<B * RS, 128, 0, stream>>>(h3f, gid, part, N);
  k_rsum<<<B, 128, 0, stream>>>(part, outp);
}